// Round 4
// baseline (318.297 us; speedup 1.0000x reference)
//
#include <hip/hip_runtime.h>
#include <hip/hip_bf16.h>
#include <cfloat>

// VQ-VAE vector quantizer.  N=262144 rows x D=100, K=512 codes.
// out[0..N*D-1] = quantized (fp32-exact gather); out[N*D]=mse; out[N*D+1]=0.25*mse.
//
// R4: R3's MFMA core + fully coalesced memory paths.
//  - A: wave stages 32 rows coalesced -> bf16 -> wave-private LDS tile ->
//       fragment ds_read_b64 (2-way conflicts only). No 400B-stride gathers.
//  - B: codebook pre-converted to bf16 fragment order in ws (L2-resident, lane-contiguous).
//  - Epilogue: lane-linear float4 writes; emb gather reads are per-row contiguous.
//  - Loss: sum_rows(||x_bf||^2 + e2 - 2<x,e>_bf) — identical to score math.
//
// ws: ws_f[0] = loss accum; ws_f[16..528) = e2[k] (fp32);
//     bytes [4096..4096+131072) = bf16 codebook, order [chunk16][s4][code32][pos32].

#define N_ROWS (64 * 64 * 64)
#define D 100
#define KCODES 512
#define CB_OFF 4096
#define E2_OFF 16

typedef __attribute__((ext_vector_type(8))) short short8;
typedef __attribute__((ext_vector_type(4))) float f32x4;

__device__ __forceinline__ unsigned short f2bf(float f) {
    union { float f; unsigned u; } v; v.f = f;
    unsigned r = v.u + 0x7FFF + ((v.u >> 16) & 1);   // RNE
    return (unsigned short)(r >> 16);
}
__device__ __forceinline__ unsigned pk2(float a, float b) {   // v_cvt_pk_bf16_f32 (RNE)
    union { __hip_bfloat162 h; unsigned u; } c;
    c.h = __float22bfloat162_rn(make_float2(a, b));
    return c.u;
}
__device__ __forceinline__ float bf2f(short s) {
    union { unsigned u; float f; } v; v.u = ((unsigned)(unsigned short)s) << 16;
    return v.f;
}

// ---- init: one wave per code ----
__global__ __launch_bounds__(64) void vq_init(const float* __restrict__ emb,
                                              float* __restrict__ ws) {
    const int code = blockIdx.x, l = threadIdx.x;
    const float* e = emb + code * D;
    if (code == 0 && l == 0) ws[0] = 0.0f;
    float a = e[l];
    float b = (l < D - 64) ? e[64 + l] : 0.0f;
    float p = fmaf(a, a, b * b);
#pragma unroll
    for (int off = 32; off; off >>= 1) p += __shfl_xor(p, off);
    if (l == 0) ws[E2_OFF + code] = p;

    unsigned short* cb = (unsigned short*)((char*)ws + CB_OFF);
    const int chunk = code >> 5, ci = code & 31;
#pragma unroll
    for (int pass = 0; pass < 2; ++pass) {
        int s = pass * 2 + (l >> 5);
        int pos = l & 31;                 // pos = quad*8 + j
        int k = s * 32 + pos;
        float f = (k < D) ? e[k] : 0.0f;
        cb[(((chunk * 4 + s) * 32 + ci) * 32) + pos] = f2bf(f);
    }
}

// ---- main: 4 waves/block, 32 rows/wave (2 M-tiles), 16 chunks of 32 codes ----
__global__ __launch_bounds__(256, 4) void vq_main(const float* __restrict__ x,
                                                  const float* __restrict__ emb,
                                                  float* __restrict__ ws,
                                                  float* __restrict__ out) {
    __shared__ unsigned long long tile[4][800];   // 32 rows x 100 bf16, wave-private
    __shared__ int widx[4][32];

    const int tid = threadIdx.x, wave = tid >> 6, lane = tid & 63;
    const int quad = lane >> 4, lr = lane & 15;
    const long wrow = ((long)blockIdx.x * 4 + wave) * 32;
    unsigned long long* t = tile[wave];

    // ---- stage 32 rows: coalesced float4 loads (batched), cvt bf16, linear LDS ----
    const float4* __restrict__ xg = (const float4*)(x + wrow * D);
    float4 v[13];
#pragma unroll
    for (int i = 0; i < 13; ++i) {
        int g = i * 64 + lane;
        if (g < 800) v[i] = xg[g];
    }
#pragma unroll
    for (int i = 0; i < 13; ++i) {
        int g = i * 64 + lane;
        if (g < 800)
            t[g] = ((unsigned long long)pk2(v[i].z, v[i].w) << 32) | pk2(v[i].x, v[i].y);
    }

    // ---- fragments (ds_read_b64 pairs) + norms from bf16 ----
    short8 A[2][4];
    float xnorm[2];
#pragma unroll
    for (int m = 0; m < 2; ++m) {
        const int row = m * 16 + lr;
        float nrm = 0.0f;
#pragma unroll
        for (int s = 0; s < 4; ++s) {
            union { unsigned long long u[2]; short8 v; } fr;
            if (s < 3) {
                fr.u[0] = t[row * 25 + s * 8 + quad * 2];
                fr.u[1] = t[row * 25 + s * 8 + quad * 2 + 1];
            } else {
                fr.u[0] = (quad == 0) ? t[row * 25 + 24] : 0ull;  // k=96..99
                fr.u[1] = 0ull;                                    // k>=100 pad
            }
            A[m][s] = fr.v;
#pragma unroll
            for (int j = 0; j < 8; ++j) {
                float fx = bf2f(fr.v[j]);
                nrm = fmaf(fx, fx, nrm);
            }
        }
        nrm += __shfl_xor(nrm, 16);   // sum k-slices across quads
        nrm += __shfl_xor(nrm, 32);
        xnorm[m] = nrm;
    }

    const unsigned short* __restrict__ cb = (const unsigned short*)((const char*)ws + CB_OFF);
    const float* __restrict__ e2g = ws + E2_OFF;

    float    runmin[2][4];
    unsigned runidx[2][4];
#pragma unroll
    for (int m = 0; m < 2; ++m)
#pragma unroll
        for (int r = 0; r < 4; ++r) { runmin[m][r] = FLT_MAX; runidx[m][r] = 0; }

#pragma unroll 2
    for (int chunk = 0; chunk < 16; ++chunk) {
        short8 B[2][4];   // lane-contiguous 16B loads from L1/L2-resident fragment table
#pragma unroll
        for (int tt = 0; tt < 2; ++tt)
#pragma unroll
            for (int s = 0; s < 4; ++s)
                B[tt][s] = *(const short8*)(cb +
                    (((chunk * 4 + s) * 32 + tt * 16 + lr) * 32) + quad * 8);
        float e2v0 = e2g[chunk * 32 + lr];
        float e2v1 = e2g[chunk * 32 + 16 + lr];

        f32x4 acc[2][2];
#pragma unroll
        for (int m = 0; m < 2; ++m)
#pragma unroll
            for (int tt = 0; tt < 2; ++tt) acc[m][tt] = (f32x4){0.f, 0.f, 0.f, 0.f};

#pragma unroll
        for (int s = 0; s < 4; ++s)
#pragma unroll
            for (int m = 0; m < 2; ++m)
#pragma unroll
                for (int tt = 0; tt < 2; ++tt)
                    acc[m][tt] = __builtin_amdgcn_mfma_f32_16x16x32_bf16(
                        A[m][s], B[tt][s], acc[m][tt], 0, 0, 0);

        // fold: score = e2 - 2<x,e>;  C layout: row=quad*4+r, col=lr
#pragma unroll
        for (int m = 0; m < 2; ++m)
#pragma unroll
            for (int tt = 0; tt < 2; ++tt) {
                float e2v = tt ? e2v1 : e2v0;
                unsigned code = chunk * 32 + tt * 16 + lr;
#pragma unroll
                for (int r = 0; r < 4; ++r) {
                    float sc = fmaf(-2.0f, acc[m][tt][r], e2v);
                    if (sc < runmin[m][r]) { runmin[m][r] = sc; runidx[m][r] = code; }
                }
            }
    }

    // ---- argmin across the 16 columns (xor 8,4,2,1 stays inside the quad) ----
    float lsum = 0.0f;
#pragma unroll
    for (int m = 0; m < 2; ++m)
#pragma unroll
        for (int r = 0; r < 4; ++r) {
            float    s = runmin[m][r];
            unsigned i = runidx[m][r];
#pragma unroll
            for (int off = 8; off >= 1; off >>= 1) {
                float    os = __shfl_xor(s, off);
                unsigned oi = (unsigned)__shfl_xor((int)i, off);
                if (os < s || (os == s && oi < i)) { s = os; i = oi; }
            }
            if (lr == quad * 4 + r) {                    // writer lane owns this row
                lsum += xnorm[m] + s;                    // ||x||^2 + e2 - 2<x,e>
                widx[wave][m * 16 + quad * 4 + r] = (int)i;
            }
        }
#pragma unroll
    for (int off = 32; off >= 1; off >>= 1) lsum += __shfl_xor(lsum, off);
    if (lane == 0) atomicAdd(ws, lsum);

    __syncthreads();   // make widx visible (cheap; also orders LDS reuse)

    // ---- gather winners + coalesced float4 writes ----
    const int* wi = widx[wave];
    float4* __restrict__ og = (float4*)(out + wrow * D);
#pragma unroll
    for (int i = 0; i < 13; ++i) {
        int g = i * 64 + lane;
        if (g < 800) {
            int row = g / 25;           // magic-div (const divisor)
            int c4  = g - row * 25;
            int idx = wi[row];
            og[g] = *(const float4*)(emb + idx * D + c4 * 4);
        }
    }
}

// ---- finalize ----
__global__ void vq_final(const float* __restrict__ ws, float* __restrict__ out) {
    float mse = ws[0] / (float)((long)N_ROWS * D);
    out[(long)N_ROWS * D]     = mse;
    out[(long)N_ROWS * D + 1] = 0.25f * mse;
}

extern "C" void kernel_launch(void* const* d_in, const int* in_sizes, int n_in,
                              void* d_out, int out_size, void* d_ws, size_t ws_size,
                              hipStream_t stream) {
    const float* x   = (const float*)d_in[0];
    const float* emb = (const float*)d_in[1];
    float* out = (float*)d_out;
    float* ws  = (float*)d_ws;

    vq_init<<<KCODES, 64, 0, stream>>>(emb, ws);
    vq_main<<<N_ROWS / 128, 256, 0, stream>>>(x, emb, ws, out);
    vq_final<<<1, 1, 0, stream>>>(ws, out);
}

// Round 5
// 232.663 us; speedup vs baseline: 1.3681x; 1.3681x over previous
//
#include <hip/hip_runtime.h>
#include <hip/hip_bf16.h>
#include <cfloat>

// VQ-VAE vector quantizer.  N=262144 rows x D=100, K=512 codes.
// out[0..N*D-1] = quantized (fp32-exact gather); out[N*D]=mse; out[N*D+1]=0.25*mse.
//
// R5: M=4 MFMA frame (64 rows/wave, 256/block) +
//  - B chunk shared across the block via double-buffered LDS (4x less L2 traffic),
//    register-prefetched one chunk ahead; cb stored in lane-linear granule order
//    so both the staging loads and the ds_read_b128 frag reads are conflict-free.
//  - A prologue: 28 independent scattered 16B loads into av[4][7] (ILP batch),
//    single drain, then bf16 convert. launch_bounds(256,2) so regs are available.
//  - Epilogue: coalesced g/25 gather+store (R4-proven on WRITE_SIZE).
//
// ws: ws_f[0] = loss accum; ws_f[16..528) = e2[k] (fp32);
//     bytes [4096..4096+131072): bf16 cb; chunk c granule layout (16B granules):
//     granule g = (s*2+tt)*64 + quad*16 + lr  holds code (c*32+tt*16+lr),
//     k = s*32+quad*8+{0..7}  (zero-padded for k>=100).

#define N_ROWS (64 * 64 * 64)
#define D 100
#define KCODES 512
#define CB_OFF 4096
#define E2_OFF 16

typedef __attribute__((ext_vector_type(8))) short short8;
typedef __attribute__((ext_vector_type(4))) float f32x4;

__device__ __forceinline__ unsigned short f2bf(float f) {
    union { float f; unsigned u; } v; v.f = f;
    unsigned r = v.u + 0x7FFF + ((v.u >> 16) & 1);   // RNE
    return (unsigned short)(r >> 16);
}
__device__ __forceinline__ unsigned pk2(float a, float b) {   // packed bf16 cvt (RNE)
    union { __hip_bfloat162 h; unsigned u; } c;
    c.h = __float22bfloat162_rn(make_float2(a, b));
    return c.u;
}
__device__ __forceinline__ short8 pack8(const float4& a, const float4& b) {
    union { unsigned u[4]; short8 v; } r;
    r.u[0] = pk2(a.x, a.y); r.u[1] = pk2(a.z, a.w);
    r.u[2] = pk2(b.x, b.y); r.u[3] = pk2(b.z, b.w);
    return r.v;
}

// ---- init: one wave per code ----
__global__ __launch_bounds__(64) void vq_init(const float* __restrict__ emb,
                                              float* __restrict__ ws) {
    const int code = blockIdx.x, l = threadIdx.x;
    const float* e = emb + code * D;
    if (code == 0 && l == 0) ws[0] = 0.0f;
    float a = e[l];
    float b = (l < D - 64) ? e[64 + l] : 0.0f;
    float p = fmaf(a, a, b * b);
#pragma unroll
    for (int off = 32; off; off >>= 1) p += __shfl_xor(p, off);
    if (l == 0) ws[E2_OFF + code] = p;

    // cb granules: 16 per code, written by lanes 0..15 (8 shorts each)
    if (l < 16) {
        const int s = l >> 2, q = l & 3;
        short8 v;
#pragma unroll
        for (int j = 0; j < 8; ++j) {
            int k = s * 32 + q * 8 + j;
            v[j] = (k < D) ? (short)f2bf(e[k]) : (short)0;
        }
        const int chunk = code >> 5, ci = code & 31;
        const int tt = ci >> 4, lr = ci & 15;
        unsigned short* cb = (unsigned short*)((char*)ws + CB_OFF);
        // short offset = chunk*4096 + granule*8, granule = (s*2+tt)*64 + q*16 + lr
        *(short8*)(cb + chunk * 4096 + ((s * 2 + tt) * 64 + q * 16 + lr) * 8) = v;
    }
}

// ---- main: 4 waves/block, 64 rows/wave (M=4), B via double-buffered LDS ----
__global__ __launch_bounds__(256, 2) void vq_main(const float* __restrict__ x,
                                                  const float* __restrict__ emb,
                                                  float* __restrict__ ws,
                                                  float* __restrict__ out) {
    __shared__ uint4  bbuf[2][512];   // 2 x 8 KB B chunk buffers
    __shared__ float  e2s[KCODES];    // 2 KB
    __shared__ int    widx[256];
    __shared__ float  wsum[4];

    const int tid = threadIdx.x, wave = tid >> 6, lane = tid & 63;
    const int quad = lane >> 4, lr = lane & 15;
    const long brow = (long)blockIdx.x * 256;
    const long wrow = brow + wave * 64;

    // ---- A: 28 independent scattered loads (batched), then convert ----
    float4 av[4][7];
#pragma unroll
    for (int m = 0; m < 4; ++m) {
        const float* xr = x + (wrow + m * 16 + lr) * D + quad * 8;
        av[m][0] = *(const float4*)(xr);
        av[m][1] = *(const float4*)(xr + 4);
        av[m][2] = *(const float4*)(xr + 32);
        av[m][3] = *(const float4*)(xr + 36);
        av[m][4] = *(const float4*)(xr + 64);
        av[m][5] = *(const float4*)(xr + 68);
        av[m][6] = *(const float4*)(x + (wrow + m * 16 + lr) * D + 96);  // same addr all quads
    }

    // ---- B chunk 0 + e2 staging (issued while A loads are in flight) ----
    const uint4* __restrict__ cbg = (const uint4*)((const char*)ws + CB_OFF);
    uint4 st0 = cbg[wave * 128 + lane];
    uint4 st1 = cbg[wave * 128 + 64 + lane];
    const float* __restrict__ e2g = ws + E2_OFF;
    e2s[tid]       = e2g[tid];
    e2s[256 + tid] = e2g[256 + tid];

    // ---- convert A -> fragments + fp32 norms ----
    short8 A[4][4];
    float  xnorm[4];
#pragma unroll
    for (int m = 0; m < 4; ++m) {
        float4 z = av[m][6];
        if (quad != 0) z = make_float4(0.f, 0.f, 0.f, 0.f);   // tail only in quad 0
        float nrm = 0.f;
#pragma unroll
        for (int i = 0; i < 6; ++i) {
            float4 f = av[m][i];
            nrm = fmaf(f.x, f.x, nrm); nrm = fmaf(f.y, f.y, nrm);
            nrm = fmaf(f.z, f.z, nrm); nrm = fmaf(f.w, f.w, nrm);
        }
        nrm = fmaf(z.x, z.x, nrm); nrm = fmaf(z.y, z.y, nrm);
        nrm = fmaf(z.z, z.z, nrm); nrm = fmaf(z.w, z.w, nrm);
        A[m][0] = pack8(av[m][0], av[m][1]);
        A[m][1] = pack8(av[m][2], av[m][3]);
        A[m][2] = pack8(av[m][4], av[m][5]);
        A[m][3] = pack8(z, make_float4(0.f, 0.f, 0.f, 0.f));
        nrm += __shfl_xor(nrm, 16);
        nrm += __shfl_xor(nrm, 32);
        xnorm[m] = nrm;
    }

    bbuf[0][wave * 128 + lane]      = st0;
    bbuf[0][wave * 128 + 64 + lane] = st1;
    __syncthreads();

    float    runmin[4][4];
    unsigned runidx[4][4];
#pragma unroll
    for (int m = 0; m < 4; ++m)
#pragma unroll
        for (int r = 0; r < 4; ++r) { runmin[m][r] = FLT_MAX; runidx[m][r] = 0; }

    for (int c = 0; c < 16; ++c) {
        const int p = c & 1;
        uint4 n0, n1;
        if (c < 15) {                      // prefetch next chunk into regs
            n0 = cbg[(c + 1) * 512 + wave * 128 + lane];
            n1 = cbg[(c + 1) * 512 + wave * 128 + 64 + lane];
        }

        // B fragments: lane-linear ds_read_b128, conflict-free
        const short8* __restrict__ bl = (const short8*)&bbuf[p][0];
        short8 B[2][4];
#pragma unroll
        for (int s = 0; s < 4; ++s) {
            B[0][s] = bl[(s * 2 + 0) * 64 + lane];
            B[1][s] = bl[(s * 2 + 1) * 64 + lane];
        }
        float e2v0 = e2s[c * 32 + lr];
        float e2v1 = e2s[c * 32 + 16 + lr];

        f32x4 acc[4][2];
#pragma unroll
        for (int m = 0; m < 4; ++m) {
            acc[m][0] = (f32x4){0.f, 0.f, 0.f, 0.f};
            acc[m][1] = (f32x4){0.f, 0.f, 0.f, 0.f};
        }
#pragma unroll
        for (int s = 0; s < 4; ++s)
#pragma unroll
            for (int m = 0; m < 4; ++m) {
                acc[m][0] = __builtin_amdgcn_mfma_f32_16x16x32_bf16(A[m][s], B[0][s], acc[m][0], 0, 0, 0);
                acc[m][1] = __builtin_amdgcn_mfma_f32_16x16x32_bf16(A[m][s], B[1][s], acc[m][1], 0, 0, 0);
            }

        // fold: score = e2 - 2<x,e>; C layout row=quad*4+r, col=lr
#pragma unroll
        for (int m = 0; m < 4; ++m)
#pragma unroll
            for (int tt = 0; tt < 2; ++tt) {
                float e2v = tt ? e2v1 : e2v0;
                unsigned code = c * 32 + tt * 16 + lr;
#pragma unroll
                for (int r = 0; r < 4; ++r) {
                    float sc = fmaf(-2.0f, acc[m][tt][r], e2v);
                    if (sc < runmin[m][r]) { runmin[m][r] = sc; runidx[m][r] = code; }
                }
            }

        if (c < 15) {
            bbuf[p ^ 1][wave * 128 + lane]      = n0;
            bbuf[p ^ 1][wave * 128 + 64 + lane] = n1;
        }
        __syncthreads();
    }

    // ---- per-row argmin across the 16 columns (xor 8,4,2,1 stays in quad) ----
    float lsum = 0.0f;
#pragma unroll
    for (int m = 0; m < 4; ++m)
#pragma unroll
        for (int r = 0; r < 4; ++r) {
            float    s = runmin[m][r];
            unsigned i = runidx[m][r];
#pragma unroll
            for (int off = 8; off >= 1; off >>= 1) {
                float    os = __shfl_xor(s, off);
                unsigned oi = (unsigned)__shfl_xor((int)i, off);
                if (os < s || (os == s && oi < i)) { s = os; i = oi; }
            }
            if (lr == quad * 4 + r) {                  // writer lane for this row
                lsum += xnorm[m] + s;                  // ||x||^2 + e2 - 2<x,e>
                widx[wave * 64 + m * 16 + quad * 4 + r] = (int)i;
            }
        }
#pragma unroll
    for (int off = 32; off >= 1; off >>= 1) lsum += __shfl_xor(lsum, off);
    if (lane == 0) wsum[wave] = lsum;
    __syncthreads();                                   // wsum + widx visible
    if (tid == 0) atomicAdd(ws, wsum[0] + wsum[1] + wsum[2] + wsum[3]);

    // ---- coalesced epilogue: 6400 float4 = 256 rows x 25, batched 5-deep ----
    const float4* __restrict__ ef = (const float4*)emb;   // 25 float4 per row, exact
    float4* __restrict__ og = (float4*)(out + brow * D);
#pragma unroll
    for (int i = 0; i < 25; i += 5) {
        float4 q[5];
        int    gi[5];
#pragma unroll
        for (int u = 0; u < 5; ++u) {
            int g = (i + u) * 256 + tid;
            int row = g / 25;                 // const-divisor magic div
            int c4  = g - row * 25;
            gi[u] = g;
            q[u]  = ef[(long)widx[row] * 25 + c4];
        }
#pragma unroll
        for (int u = 0; u < 5; ++u) og[gi[u]] = q[u];
    }
}

// ---- finalize ----
__global__ void vq_final(const float* __restrict__ ws, float* __restrict__ out) {
    float mse = ws[0] / (float)((long)N_ROWS * D);
    out[(long)N_ROWS * D]     = mse;
    out[(long)N_ROWS * D + 1] = 0.25f * mse;
}

extern "C" void kernel_launch(void* const* d_in, const int* in_sizes, int n_in,
                              void* d_out, int out_size, void* d_ws, size_t ws_size,
                              hipStream_t stream) {
    const float* x   = (const float*)d_in[0];
    const float* emb = (const float*)d_in[1];
    float* out = (float*)d_out;
    float* ws  = (float*)d_ws;

    vq_init<<<KCODES, 64, 0, stream>>>(emb, ws);
    vq_main<<<N_ROWS / 256, 256, 0, stream>>>(x, emb, ws, out);
    vq_final<<<1, 1, 0, stream>>>(ws, out);
}